// Round 8
// baseline (247.388 us; speedup 1.0000x reference)
//
#include <hip/hip_runtime.h>
#include <stdint.h>
#include <math.h>

#define D 128
#define EDIM 5
#define QSCALE 0.1803368801111204f   // 0.125 * log2(e)

typedef __attribute__((ext_vector_type(8))) short bf16x8;
typedef __attribute__((ext_vector_type(4))) float f32x4;

__device__ __forceinline__ float fexp2(float x) {
  return __builtin_amdgcn_exp2f(x);    // v_exp_f32 (2^x)
}

__device__ __forceinline__ ushort f2b(float f) {
  union { float f; uint u; } v; v.f = f;
  uint u = v.u;
  return (ushort)((u + 0x7fff + ((u >> 16) & 1)) >> 16);   // RNE
}
__device__ __forceinline__ float blo(uint u) {
  union { uint u; float f; } v; v.u = u << 16; return v.f;
}
__device__ __forceinline__ float bhi(uint u) {
  union { uint u; float f; } v; v.u = u & 0xffff0000u; return v.f;
}

// ======================= utility kernels =======================

__global__ void hist_kernel(const int* __restrict__ ei, int* __restrict__ deg, int E) {
  int e = blockIdx.x * blockDim.x + threadIdx.x;
  if (e < E) atomicAdd(&deg[ei[(size_t)E + e]], 1);
}

// ---- hierarchical exclusive scan over deg[N] -> off[N+1] ----
__global__ __launch_bounds__(256) void scan_p1(const int* __restrict__ deg,
                                               int* __restrict__ off,
                                               int* __restrict__ blockSum, int n4) {
  __shared__ int waveTot[4];
  int idx = blockIdx.x * 256 + threadIdx.x;
  int4 v = make_int4(0, 0, 0, 0);
  if (idx < n4) v = ((const int4*)deg)[idx];
  int c0 = v.x, c1 = c0 + v.y, c2 = c1 + v.z, c3 = c2 + v.w;
  int tot = c3;
  int lane = threadIdx.x & 63, w = threadIdx.x >> 6;
  int incl = tot;
#pragma unroll
  for (int ofs = 1; ofs < 64; ofs <<= 1) {
    int t = __shfl_up(incl, ofs, 64);
    if (lane >= ofs) incl += t;
  }
  if (lane == 63) waveTot[w] = incl;
  __syncthreads();
  int wbase = 0;
  for (int i = 0; i < w; ++i) wbase += waveTot[i];
  int excl = wbase + incl - tot;
  if (idx < n4) {
    int4 o;
    o.x = excl; o.y = excl + c0; o.z = excl + c1; o.w = excl + c2;
    ((int4*)off)[idx] = o;
  }
  if (threadIdx.x == 255) blockSum[blockIdx.x] = wbase + incl;
}

__global__ void scan_p2(const int* __restrict__ blockSum, int* __restrict__ blockBase,
                        int* __restrict__ off_last, int nb) {
  int lane = threadIdx.x;            // 64 threads, nb <= 64
  int v = (lane < nb) ? blockSum[lane] : 0;
  int incl = v;
#pragma unroll
  for (int ofs = 1; ofs < 64; ofs <<= 1) {
    int t = __shfl_up(incl, ofs, 64);
    if (lane >= ofs) incl += t;
  }
  if (lane < nb) blockBase[lane] = incl - v;
  if (lane == 63) *off_last = incl;
}

// add block bases; also zero cursor
__global__ __launch_bounds__(256) void scan_p3(int* __restrict__ off,
                                               const int* __restrict__ blockBase,
                                               int* __restrict__ cursor, int n4) {
  int idx = blockIdx.x * 256 + threadIdx.x;
  if (idx >= n4) return;
  int b = blockBase[blockIdx.x];
  int4 v = ((int4*)off)[idx];
  v.x += b; v.y += b; v.z += b; v.w += b;
  ((int4*)off)[idx] = v;
  ((int4*)cursor)[idx] = make_int4(0, 0, 0, 0);
}

// sort edges by dst; edge payload = {ea bf16 x5, src} in ONE uint4
__global__ void scatter_kernel(const int* __restrict__ ei, const float* __restrict__ ea,
                               const int* __restrict__ off, int* __restrict__ cursor,
                               uint4* __restrict__ easrt, int E) {
  int e = blockIdx.x * blockDim.x + threadIdx.x;
  if (e >= E) return;
  int dst = ei[(size_t)E + e];
  int pos = off[dst] + atomicAdd(&cursor[dst], 1);
  const float* p = ea + (size_t)e * EDIM;
  uint e0 = f2b(p[0]), e1 = f2b(p[1]), e2 = f2b(p[2]), e3 = f2b(p[3]), e4 = f2b(p[4]);
  easrt[pos] = make_uint4(e0 | (e1 << 16), e2 | (e3 << 16), e4, (uint)ei[e]);
}

// ======================= weight prep (+ deg zero fused) =======================
__global__ void cvt_w_kernel(const float* __restrict__ Wq, const float* __restrict__ Wk,
                             const float* __restrict__ Wv, const float* __restrict__ Wr,
                             const float* __restrict__ bq, const float* __restrict__ bk,
                             const float* __restrict__ bv, const float* __restrict__ br,
                             const float* __restrict__ We, const float* __restrict__ Wp,
                             ushort* __restrict__ Wcat, float* __restrict__ bcat,
                             ushort* __restrict__ Wpb, int* __restrict__ deg, int N) {
  int i = blockIdx.x * blockDim.x + threadIdx.x;
  if (i < N) deg[i] = 0;
  if (i < 512 * D) {
    int r = i >> 7;
    float v;
    if (r < 128)      v = Wq[i] * QSCALE;
    else if (r < 256) v = Wk[i - 128 * D];
    else if (r < 384) v = Wv[i - 256 * D];
    else              v = Wr[i - 384 * D];
    Wcat[i] = f2b(v);
  } else if (i < 512 * D + 128 * D) {
    int ie = i - 512 * D;
    int r = ie >> 7, c = ie & 127;          // Wcat row 512+r
    int h = r >> 3, j = r & 7;
    float v = 0.f;
    if (h < 2 && j < 5) {
      for (int d = 0; d < 64; ++d) {
        int dd = h * 64 + d;
        v += We[(size_t)dd * EDIM + j] * QSCALE * Wq[(size_t)dd * D + c];
      }
    }
    Wcat[(size_t)(512 + r) * D + c] = f2b(v);
  }
  if (i < D * D) Wpb[i] = f2b(Wp[i]);
  if (i < 512) {
    float v = (i < 128) ? bq[i] * QSCALE
            : (i < 256) ? bk[i - 128]
            : (i < 384) ? bv[i - 256] : br[i - 384];
    bcat[i] = v;
  } else if (i < 640) {
    int t = i - 512;
    int h = t >> 3, j = t & 7;
    float v = 0.f;
    if (h < 2 && j < 5) {
      for (int d = 0; d < 64; ++d) {
        int dd = h * 64 + d;
        v += bq[dd] * QSCALE * We[(size_t)dd * EDIM + j];
      }
    }
    bcat[i] = v;
  }
}

// ======================= fused projection GEMM (BM=128) =======================
__global__ __launch_bounds__(256) void proj_gemm_kernel(
    const float* __restrict__ x, const ushort* __restrict__ Wcat,
    const float* __restrict__ bcat,
    ushort* __restrict__ q, ushort* __restrict__ kv, ushort* __restrict__ xr,
    float* __restrict__ qwe, int M)
{
  __shared__ __attribute__((aligned(16))) ushort As[128][128];
  __shared__ __attribute__((aligned(16))) ushort Bs[128][128];
  const int tid = threadIdx.x;
  const int rowBase = blockIdx.x * 128;

  // stage A with fused f32->bf16 convert
#pragma unroll
  for (int it = 0; it < 8; ++it) {
    int i = it * 256 + tid;
    int r = i >> 4, c = i & 15;
    int gr = rowBase + r;
    float4 a0 = make_float4(0.f, 0.f, 0.f, 0.f), a1 = a0;
    if (gr < M) {
      a0 = *(const float4*)(x + (size_t)gr * D + c * 8);
      a1 = *(const float4*)(x + (size_t)gr * D + c * 8 + 4);
    }
    uint4 w;
    w.x = (uint)f2b(a0.x) | ((uint)f2b(a0.y) << 16);
    w.y = (uint)f2b(a0.z) | ((uint)f2b(a0.w) << 16);
    w.z = (uint)f2b(a1.x) | ((uint)f2b(a1.y) << 16);
    w.w = (uint)f2b(a1.z) | ((uint)f2b(a1.w) << 16);
    *(uint4*)(&As[r][(c ^ (r & 7)) * 8]) = w;
  }

  const int lane = tid & 63;
  const int wave = tid >> 6;
  const int wm = (wave >> 1) * 64;
  const int wn = (wave & 1) * 64;
  const int lrow = lane & 15;
  const int kgrp = lane >> 4;
  const int orow = (lane >> 4) * 4;
  const int ocol = lane & 15;

  for (int cb = 0; cb < 5; ++cb) {
    // stage B block (cb=4: only rows 0-15 are live)
#pragma unroll
    for (int it = 0; it < 8; ++it) {
      int i = it * 256 + tid;
      int r = i >> 4, c = i & 15;
      if (cb == 4 && r >= 16) continue;
      uint4 bv4 = *(const uint4*)(Wcat + (size_t)(cb * 128 + r) * D + c * 8);
      *(uint4*)(&Bs[r][(c ^ (r & 7)) * 8]) = bv4;
    }
    __syncthreads();

    f32x4 acc[4][4] = {};
#pragma unroll
    for (int ks = 0; ks < 4; ++ks) {
      int chunk = ks * 4 + kgrp;
      bf16x8 a[4], b[4];
#pragma unroll
      for (int m = 0; m < 4; ++m) {
        int r = wm + m * 16 + lrow;
        a[m] = *(const bf16x8*)&As[r][(chunk ^ (r & 7)) * 8];
      }
#pragma unroll
      for (int n = 0; n < 4; ++n) {
        int r = wn + n * 16 + lrow;
        b[n] = *(const bf16x8*)&Bs[r][(chunk ^ (r & 7)) * 8];
      }
#pragma unroll
      for (int m = 0; m < 4; ++m)
#pragma unroll
        for (int n = 0; n < 4; ++n) {
          if (cb == 4 && (wn + n * 16) >= 16) continue;
          acc[m][n] = __builtin_amdgcn_mfma_f32_16x16x32_bf16(a[m], b[n], acc[m][n], 0, 0, 0);
        }
    }

#pragma unroll
    for (int m = 0; m < 4; ++m) {
#pragma unroll
      for (int n = 0; n < 4; ++n) {
        if (cb == 4 && (wn + n * 16) >= 16) continue;
        int col = cb * 128 + wn + n * 16 + ocol;
        float bi = bcat[col];
        int sel = col >> 7, c = col & 127;
#pragma unroll
        for (int ii = 0; ii < 4; ++ii) {
          int gr = rowBase + wm + m * 16 + orow + ii;
          if (gr >= M) continue;
          float v = acc[m][n][ii] + bi;
          if (sel == 0)      q[(size_t)gr * D + c] = f2b(v);
          else if (sel == 1) kv[(size_t)gr * 2 * D + c] = f2b(v);
          else if (sel == 2) kv[(size_t)gr * 2 * D + D + c] = f2b(v);
          else if (sel == 3) xr[(size_t)gr * D + c] = f2b(v);
          else if (c < 16)   qwe[(size_t)gr * 16 + c] = v;
        }
      }
    }
    __syncthreads();
  }
}

// ======================= output projection GEMM (BM=128) =======================
__global__ __launch_bounds__(256) void out_gemm_kernel(
    const ushort* __restrict__ g, const ushort* __restrict__ Wpb,
    const float* __restrict__ bp, float* __restrict__ out, int M)
{
  __shared__ __attribute__((aligned(16))) ushort As[128][128];
  __shared__ __attribute__((aligned(16))) ushort Bs[128][128];
  const int tid = threadIdx.x;
  const int rowBase = blockIdx.x * 128;

#pragma unroll
  for (int it = 0; it < 8; ++it) {
    int i = it * 256 + tid;
    int r = i >> 4, c = i & 15;
    int gr = rowBase + r;
    uint4 av = make_uint4(0, 0, 0, 0);
    if (gr < M) av = *(const uint4*)(g + (size_t)gr * D + c * 8);
    *(uint4*)(&As[r][(c ^ (r & 7)) * 8]) = av;
  }
#pragma unroll
  for (int it = 0; it < 8; ++it) {
    int i = it * 256 + tid;
    int r = i >> 4, c = i & 15;
    uint4 bv4 = *(const uint4*)(Wpb + (size_t)r * D + c * 8);
    *(uint4*)(&Bs[r][(c ^ (r & 7)) * 8]) = bv4;
  }
  __syncthreads();

  const int lane = tid & 63;
  const int wave = tid >> 6;
  const int wm = (wave >> 1) * 64;
  const int wn = (wave & 1) * 64;
  const int lrow = lane & 15;
  const int kgrp = lane >> 4;

  f32x4 acc[4][4] = {};
#pragma unroll
  for (int ks = 0; ks < 4; ++ks) {
    int chunk = ks * 4 + kgrp;
    bf16x8 a[4], b[4];
#pragma unroll
    for (int m = 0; m < 4; ++m) {
      int r = wm + m * 16 + lrow;
      a[m] = *(const bf16x8*)&As[r][(chunk ^ (r & 7)) * 8];
    }
#pragma unroll
    for (int n = 0; n < 4; ++n) {
      int r = wn + n * 16 + lrow;
      b[n] = *(const bf16x8*)&Bs[r][(chunk ^ (r & 7)) * 8];
    }
#pragma unroll
    for (int m = 0; m < 4; ++m)
#pragma unroll
      for (int n = 0; n < 4; ++n)
        acc[m][n] = __builtin_amdgcn_mfma_f32_16x16x32_bf16(a[m], b[n], acc[m][n], 0, 0, 0);
  }

  const int orow = (lane >> 4) * 4;
  const int ocol = lane & 15;
#pragma unroll
  for (int m = 0; m < 4; ++m) {
#pragma unroll
    for (int n = 0; n < 4; ++n) {
      int col = wn + n * 16 + ocol;
      float bi = bp[col];
#pragma unroll
      for (int ii = 0; ii < 4; ++ii) {
        int gr = rowBase + wm + m * 16 + orow + ii;
        if (gr >= M) continue;
        out[(size_t)gr * D + col] = acc[m][n][ii] + bi;
      }
    }
  }
}

// ======================= per-node attention v5 =======================
// Persistent grid-stride waves (whole grid co-resident); per node: 16-lane
// groups, 4 edges/batch, modulo-3 pipelined loads, exp2-domain defer-max.
__global__ __launch_bounds__(256) void node_attn_kernel(
    const ushort* __restrict__ q, const ushort* __restrict__ kv,
    const ushort* __restrict__ xr, ushort* __restrict__ g,
    const float* __restrict__ qwe, const uint4* __restrict__ easrt,
    const float* __restrict__ We, const float* __restrict__ Wb,
    const int* __restrict__ off, int N)
{
  const int wid = threadIdx.x >> 6;
  const int lane = threadIdx.x & 63;
  const int grp = lane >> 4;
  const int i = lane & 15;
  const int di = i * 8;
  const int head = i >> 3;
  const int nodeStride = gridDim.x * 4;

  for (int node = blockIdx.x * 4 + wid; node < N; node += nodeStride) {

  float qr[8];
  {
    uint4 qa = *(const uint4*)(q + (size_t)node * D + di);
    qr[0] = blo(qa.x); qr[1] = bhi(qa.x); qr[2] = blo(qa.y); qr[3] = bhi(qa.y);
    qr[4] = blo(qa.z); qr[5] = bhi(qa.z); qr[6] = blo(qa.w); qr[7] = bhi(qa.w);
  }
  float qw[5];
  {
    const float* qp = qwe + (size_t)node * 16 + head * 8;
    float4 t = *(const float4*)qp;
    qw[0] = t.x; qw[1] = t.y; qw[2] = t.z; qw[3] = t.w; qw[4] = qp[4];
  }

  const int beg = off[node], end = off[node + 1];
  float m = -INFINITY, s = 0.f;
  float o[8] = {0.f, 0.f, 0.f, 0.f, 0.f, 0.f, 0.f, 0.f};
  float wea[5] = {0.f, 0.f, 0.f, 0.f, 0.f};

  if (beg < end) {
    const int em1 = end - 1;
    const int p0 = beg + grp;
    uint4 e0 = easrt[min(p0, em1)];
    uint4 e1 = easrt[min(p0 + 4, em1)];
    uint4 e2 = easrt[min(p0 + 8, em1)];
    const ushort* kp_;
    kp_ = kv + (size_t)e0.w * (2 * D);
    uint4 k0 = *(const uint4*)(kp_ + di), v0 = *(const uint4*)(kp_ + D + di);
    kp_ = kv + (size_t)e1.w * (2 * D);
    uint4 k1 = *(const uint4*)(kp_ + di), v1 = *(const uint4*)(kp_ + D + di);
    uint4 k2v = k0, v2v = v0;   // written by STEP1 before STEP3 reads them

#define ATT_STEP(PB, eA, eC, kA, vA, kC, vC)                                   \
    {                                                                          \
      int p = (PB) + grp;                                                      \
      bool valid = p < end;                                                    \
      const ushort* kpn = kv + (size_t)(eC).w * (2 * D);                       \
      (kC) = *(const uint4*)(kpn + di);                                        \
      (vC) = *(const uint4*)(kpn + D + di);                                    \
      float ea0 = blo((eA).x), ea1 = bhi((eA).x), ea2 = blo((eA).y),           \
            ea3 = bhi((eA).y), ea4 = blo((eA).z);                              \
      (eA) = easrt[min(p + 12, em1)];                                          \
      float part = qr[0] * blo((kA).x) + qr[1] * bhi((kA).x)                   \
                 + qr[2] * blo((kA).y) + qr[3] * bhi((kA).y)                   \
                 + qr[4] * blo((kA).z) + qr[5] * bhi((kA).z)                   \
                 + qr[6] * blo((kA).w) + qr[7] * bhi((kA).w);                  \
      part += __shfl_xor(part, 1, 64);                                         \
      part += __shfl_xor(part, 2, 64);                                         \
      part += __shfl_xor(part, 4, 64);                                         \
      float eadot = qw[0] * ea0 + qw[1] * ea1 + qw[2] * ea2 + qw[3] * ea3      \
                  + qw[4] * ea4;                                               \
      float alpha = valid ? (part + eadot) : -INFINITY;                        \
      float vv0 = blo((vA).x), vv1 = bhi((vA).x), vv2 = blo((vA).y),           \
            vv3 = bhi((vA).y), vv4 = blo((vA).z), vv5 = bhi((vA).z),           \
            vv6 = blo((vA).w), vv7 = bhi((vA).w);                              \
      if (__any(alpha > m + 11.5f)) {                                          \
        float nm = fmaxf(m, alpha);                                            \
        float scale = (m > -1e30f) ? fexp2(m - nm) : 0.f;                      \
        float pw = valid ? fexp2(alpha - nm) : 0.f;                            \
        m = nm;                                                                \
        s = s * scale + pw;                                                    \
        o[0] = o[0] * scale + pw * vv0; o[1] = o[1] * scale + pw * vv1;        \
        o[2] = o[2] * scale + pw * vv2; o[3] = o[3] * scale + pw * vv3;        \
        o[4] = o[4] * scale + pw * vv4; o[5] = o[5] * scale + pw * vv5;        \
        o[6] = o[6] * scale + pw * vv6; o[7] = o[7] * scale + pw * vv7;        \
        wea[0] = wea[0] * scale + pw * ea0; wea[1] = wea[1] * scale + pw * ea1;\
        wea[2] = wea[2] * scale + pw * ea2; wea[3] = wea[3] * scale + pw * ea3;\
        wea[4] = wea[4] * scale + pw * ea4;                                    \
      } else {                                                                 \
        float pw = valid ? fexp2(alpha - m) : 0.f;                             \
        s += pw;                                                               \
        o[0] += pw * vv0; o[1] += pw * vv1; o[2] += pw * vv2;                  \
        o[3] += pw * vv3; o[4] += pw * vv4; o[5] += pw * vv5;                  \
        o[6] += pw * vv6; o[7] += pw * vv7;                                    \
        wea[0] += pw * ea0; wea[1] += pw * ea1; wea[2] += pw * ea2;            \
        wea[3] += pw * ea3; wea[4] += pw * ea4;                                \
      }                                                                        \
    }

    for (int pb = beg; pb < end; pb += 12) {
      ATT_STEP(pb,     e0, e2, k0, v0, k2v, v2v)
      ATT_STEP(pb + 4, e1, e0, k1, v1, k0, v0)
      ATT_STEP(pb + 8, e2, e1, k2v, v2v, k1, v1)
    }
#undef ATT_STEP
  }

  // merge the 4 groups (lane bits 4,5)
#pragma unroll
  for (int ofs = 16; ofs < 64; ofs <<= 1) {
    float m2 = __shfl_xor(m, ofs, 64);
    float s2 = __shfl_xor(s, ofs, 64);
    float o2[8], w2[5];
#pragma unroll
    for (int j = 0; j < 8; ++j) o2[j] = __shfl_xor(o[j], ofs, 64);
#pragma unroll
    for (int j = 0; j < 5; ++j) w2[j] = __shfl_xor(wea[j], ofs, 64);
    float nm = fmaxf(m, m2);
    float e1m = (m > -1e30f) ? fexp2(m - nm) : 0.f;
    float e2m = (m2 > -1e30f) ? fexp2(m2 - nm) : 0.f;
    s = s * e1m + s2 * e2m;
#pragma unroll
    for (int j = 0; j < 8; ++j) o[j] = o[j] * e1m + o2[j] * e2m;
#pragma unroll
    for (int j = 0; j < 5; ++j) wea[j] = wea[j] * e1m + w2[j] * e2m;
    m = nm;
  }

  float inv = (s > 0.f) ? (1.f / s) : 0.f;
#pragma unroll
  for (int j = 0; j < 8; ++j) o[j] *= inv;
#pragma unroll
  for (int j = 0; j < 5; ++j) wea[j] *= inv;

  // O += We @ wea for this lane's 8 dims
  {
    const float* wp = We + (size_t)di * EDIM;
    float4 w[10];
#pragma unroll
    for (int t = 0; t < 10; ++t) w[t] = *(const float4*)(wp + 4 * t);
#pragma unroll
    for (int r = 0; r < 8; ++r)
#pragma unroll
      for (int j = 0; j < 5; ++j) {
        int idx = r * 5 + j;
        o[r] += wea[j] * ((const float*)&w[idx >> 2])[idx & 3];
      }
  }

  // beta gate
  float xrv[8];
  {
    uint4 xa = *(const uint4*)(xr + (size_t)node * D + di);
    xrv[0] = blo(xa.x); xrv[1] = bhi(xa.x); xrv[2] = blo(xa.y); xrv[3] = bhi(xa.y);
    xrv[4] = blo(xa.z); xrv[5] = bhi(xa.z); xrv[6] = blo(xa.w); xrv[7] = bhi(xa.w);
  }
  float part = 0.f;
#pragma unroll
  for (int r = 0; r < 8; ++r) {
    float w1 = Wb[di + r] + Wb[256 + di + r];
    float w2 = Wb[128 + di + r] - Wb[256 + di + r];
    part += o[r] * w1 + xrv[r] * w2;
  }
#pragma unroll
  for (int ofs = 1; ofs < 16; ofs <<= 1) part += __shfl_xor(part, ofs, 64);
  float beta = 1.f / (1.f + __expf(-part));

  if (grp == 0) {
    uint pk[4];
#pragma unroll
    for (int r = 0; r < 4; ++r) {
      float g0 = beta * xrv[2 * r] + (1.f - beta) * o[2 * r];
      float g1 = beta * xrv[2 * r + 1] + (1.f - beta) * o[2 * r + 1];
      pk[r] = (uint)f2b(g0) | ((uint)f2b(g1) << 16);
    }
    *(uint4*)(g + (size_t)node * D + di) = make_uint4(pk[0], pk[1], pk[2], pk[3]);
  }

  }  // grid-stride node loop
}

// ======================= launch =======================

extern "C" void kernel_launch(void* const* d_in, const int* in_sizes, int n_in,
                              void* d_out, int out_size, void* d_ws, size_t ws_size,
                              hipStream_t stream)
{
  const float* x  = (const float*)d_in[0];
  const int*   ei = (const int*)d_in[1];
  const float* ea = (const float*)d_in[2];
  const float* Wq = (const float*)d_in[3];
  const float* bq = (const float*)d_in[4];
  const float* Wk = (const float*)d_in[5];
  const float* bk = (const float*)d_in[6];
  const float* Wv = (const float*)d_in[7];
  const float* bv = (const float*)d_in[8];
  const float* We = (const float*)d_in[9];
  const float* Wr = (const float*)d_in[10];
  const float* br = (const float*)d_in[11];
  const float* Wb = (const float*)d_in[12];
  const float* Wp = (const float*)d_in[13];
  const float* bp = (const float*)d_in[14];

  const int N = in_sizes[0] / D;
  const int E = in_sizes[1] / 2;
  float* out = (float*)d_out;

  char* ws = (char*)d_ws;
  size_t o = 0;
  auto alloc = [&](size_t bytes) -> void* {
    void* p = ws + o;
    o = (o + bytes + 255) & ~(size_t)255;
    return p;
  };
  ushort* q      = (ushort*)alloc((size_t)N * D * sizeof(ushort));
  ushort* kv     = (ushort*)alloc((size_t)N * 2 * D * sizeof(ushort));
  ushort* xr     = (ushort*)alloc((size_t)N * D * sizeof(ushort));
  ushort* g      = (ushort*)alloc((size_t)N * D * sizeof(ushort));
  float*  qwe    = (float*)alloc((size_t)N * 16 * sizeof(float));
  ushort* Wcat   = (ushort*)alloc((size_t)640 * D * sizeof(ushort));
  float*  bcat   = (float*)alloc(640 * sizeof(float));
  ushort* Wpb    = (ushort*)alloc((size_t)D * D * sizeof(ushort));
  int*    deg    = (int*)alloc((size_t)N * sizeof(int));
  int*    cursor = (int*)alloc((size_t)N * sizeof(int));
  int*    offs   = (int*)alloc((size_t)(N + 1) * sizeof(int));
  uint4*  easrt  = (uint4*)alloc((size_t)E * sizeof(uint4));
  int*    bsum   = (int*)alloc(64 * sizeof(int));
  int*    bbase  = (int*)alloc(64 * sizeof(int));

  const int n4 = N / 4;                    // N divisible by 4
  const int nb = (n4 + 255) / 256;         // scan blocks (<= 64)

  // weight prep first (also zeroes deg)
  cvt_w_kernel<<<(512 * D + 128 * D + 255) / 256, 256, 0, stream>>>(
      Wq, Wk, Wv, Wr, bq, bk, bv, br, We, Wp, Wcat, bcat, Wpb, deg, N);

  hist_kernel<<<(E + 255) / 256, 256, 0, stream>>>(ei, deg, E);
  scan_p1<<<nb, 256, 0, stream>>>(deg, offs, bsum, n4);
  scan_p2<<<1, 64, 0, stream>>>(bsum, bbase, offs + N, nb);
  scan_p3<<<nb, 256, 0, stream>>>(offs, bbase, cursor, n4);
  scatter_kernel<<<(E + 255) / 256, 256, 0, stream>>>(ei, ea, offs, cursor, easrt, E);

  proj_gemm_kernel<<<(N + 127) / 128, 256, 0, stream>>>(x, Wcat, bcat, q, kv, xr, qwe, N);

  int attnBlocks = (N + 3) / 4;
  if (attnBlocks > 2048) attnBlocks = 2048;
  node_attn_kernel<<<attnBlocks, 256, 0, stream>>>(q, kv, xr, g, qwe, easrt, We, Wb,
                                                   offs, N);

  out_gemm_kernel<<<(N + 127) / 128, 256, 0, stream>>>(g, Wpb, bp, out, N);
}

// Round 10
// 213.969 us; speedup vs baseline: 1.1562x; 1.1562x over previous
//
#include <hip/hip_runtime.h>
#include <stdint.h>
#include <math.h>

#define D 128
#define EDIM 5
#define QSCALE 0.1803368801111204f   // 0.125 * log2(e)

typedef __attribute__((ext_vector_type(8))) short bf16x8;
typedef __attribute__((ext_vector_type(4))) float f32x4;
typedef _Float16 h16x2 __attribute__((ext_vector_type(2)));

__device__ __forceinline__ float fexp2(float x) {
  return __builtin_amdgcn_exp2f(x);    // v_exp_f32 (2^x)
}

__device__ __forceinline__ ushort f2b(float f) {
  union { float f; uint u; } v; v.f = f;
  uint u = v.u;
  return (ushort)((u + 0x7fff + ((u >> 16) & 1)) >> 16);   // RNE
}
__device__ __forceinline__ float blo(uint u) {
  union { uint u; float f; } v; v.u = u << 16; return v.f;
}
__device__ __forceinline__ float bhi(uint u) {
  union { uint u; float f; } v; v.u = u & 0xffff0000u; return v.f;
}
__device__ __forceinline__ ushort f2h(float f) {
  union { _Float16 h; ushort u; } v; v.h = (_Float16)f;   // v_cvt_f16_f32 (RNE)
  return v.u;
}
__device__ __forceinline__ h16x2 u2h(uint u) {
  union { uint u; h16x2 h; } v; v.u = u; return v.h;
}

#if __has_builtin(__builtin_amdgcn_fdot2)
#define FDOT2(a, b, c) __builtin_amdgcn_fdot2((a), (b), (c), false)
#else
#define FDOT2(a, b, c) ((c) + (float)(a)[0] * (float)(b)[0] + (float)(a)[1] * (float)(b)[1])
#endif

// ======================= utility kernels =======================

__global__ void hist_kernel(const int* __restrict__ ei, int* __restrict__ deg, int E) {
  int e = blockIdx.x * blockDim.x + threadIdx.x;
  if (e < E) atomicAdd(&deg[ei[(size_t)E + e]], 1);
}

// ---- hierarchical exclusive scan over deg[N] -> off[N+1] ----
__global__ __launch_bounds__(256) void scan_p1(const int* __restrict__ deg,
                                               int* __restrict__ off,
                                               int* __restrict__ blockSum, int n4) {
  __shared__ int waveTot[4];
  int idx = blockIdx.x * 256 + threadIdx.x;
  int4 v = make_int4(0, 0, 0, 0);
  if (idx < n4) v = ((const int4*)deg)[idx];
  int c0 = v.x, c1 = c0 + v.y, c2 = c1 + v.z, c3 = c2 + v.w;
  int tot = c3;
  int lane = threadIdx.x & 63, w = threadIdx.x >> 6;
  int incl = tot;
#pragma unroll
  for (int ofs = 1; ofs < 64; ofs <<= 1) {
    int t = __shfl_up(incl, ofs, 64);
    if (lane >= ofs) incl += t;
  }
  if (lane == 63) waveTot[w] = incl;
  __syncthreads();
  int wbase = 0;
  for (int i = 0; i < w; ++i) wbase += waveTot[i];
  int excl = wbase + incl - tot;
  if (idx < n4) {
    int4 o;
    o.x = excl; o.y = excl + c0; o.z = excl + c1; o.w = excl + c2;
    ((int4*)off)[idx] = o;
  }
  if (threadIdx.x == 255) blockSum[blockIdx.x] = wbase + incl;
}

__global__ void scan_p2(const int* __restrict__ blockSum, int* __restrict__ blockBase,
                        int* __restrict__ off_last, int nb) {
  int lane = threadIdx.x;            // 64 threads, nb <= 64
  int v = (lane < nb) ? blockSum[lane] : 0;
  int incl = v;
#pragma unroll
  for (int ofs = 1; ofs < 64; ofs <<= 1) {
    int t = __shfl_up(incl, ofs, 64);
    if (lane >= ofs) incl += t;
  }
  if (lane < nb) blockBase[lane] = incl - v;
  if (lane == 63) *off_last = incl;
}

// add block bases; also zero cursor
__global__ __launch_bounds__(256) void scan_p3(int* __restrict__ off,
                                               const int* __restrict__ blockBase,
                                               int* __restrict__ cursor, int n4) {
  int idx = blockIdx.x * 256 + threadIdx.x;
  if (idx >= n4) return;
  int b = blockBase[blockIdx.x];
  int4 v = ((int4*)off)[idx];
  v.x += b; v.y += b; v.z += b; v.w += b;
  ((int4*)off)[idx] = v;
  ((int4*)cursor)[idx] = make_int4(0, 0, 0, 0);
}

// sort edges by dst; edge payload = {ea bf16 x5, src} in ONE uint4
__global__ void scatter_kernel(const int* __restrict__ ei, const float* __restrict__ ea,
                               const int* __restrict__ off, int* __restrict__ cursor,
                               uint4* __restrict__ easrt, int E) {
  int e = blockIdx.x * blockDim.x + threadIdx.x;
  if (e >= E) return;
  int dst = ei[(size_t)E + e];
  int pos = off[dst] + atomicAdd(&cursor[dst], 1);
  const float* p = ea + (size_t)e * EDIM;
  uint e0 = f2b(p[0]), e1 = f2b(p[1]), e2 = f2b(p[2]), e3 = f2b(p[3]), e4 = f2b(p[4]);
  easrt[pos] = make_uint4(e0 | (e1 << 16), e2 | (e3 << 16), e4, (uint)ei[e]);
}

// ======================= weight prep (+ deg zero fused) =======================
__global__ void cvt_w_kernel(const float* __restrict__ Wq, const float* __restrict__ Wk,
                             const float* __restrict__ Wv, const float* __restrict__ Wr,
                             const float* __restrict__ bq, const float* __restrict__ bk,
                             const float* __restrict__ bv, const float* __restrict__ br,
                             const float* __restrict__ We, const float* __restrict__ Wp,
                             ushort* __restrict__ Wcat, float* __restrict__ bcat,
                             ushort* __restrict__ Wpb, int* __restrict__ deg, int N) {
  int i = blockIdx.x * blockDim.x + threadIdx.x;
  if (i < N) deg[i] = 0;
  if (i < 512 * D) {
    int r = i >> 7;
    float v;
    if (r < 128)      v = Wq[i] * QSCALE;
    else if (r < 256) v = Wk[i - 128 * D];
    else if (r < 384) v = Wv[i - 256 * D];
    else              v = Wr[i - 384 * D];
    Wcat[i] = f2b(v);
  } else if (i < 512 * D + 128 * D) {
    int ie = i - 512 * D;
    int r = ie >> 7, c = ie & 127;          // Wcat row 512+r
    int h = r >> 3, j = r & 7;
    float v = 0.f;
    if (h < 2 && j < 5) {
      for (int d = 0; d < 64; ++d) {
        int dd = h * 64 + d;
        v += We[(size_t)dd * EDIM + j] * QSCALE * Wq[(size_t)dd * D + c];
      }
    }
    Wcat[(size_t)(512 + r) * D + c] = f2b(v);
  }
  if (i < D * D) Wpb[i] = f2b(Wp[i]);
  if (i < 512) {
    float v = (i < 128) ? bq[i] * QSCALE
            : (i < 256) ? bk[i - 128]
            : (i < 384) ? bv[i - 256] : br[i - 384];
    bcat[i] = v;
  } else if (i < 640) {
    int t = i - 512;
    int h = t >> 3, j = t & 7;
    float v = 0.f;
    if (h < 2 && j < 5) {
      for (int d = 0; d < 64; ++d) {
        int dd = h * 64 + d;
        v += bq[dd] * QSCALE * We[(size_t)dd * EDIM + j];
      }
    }
    bcat[i] = v;
  }
}

// ======================= fused projection GEMM (BM=64) =======================
// Outputs: q f16, kv f16 [N][256] (K|V), xr bf16, qwe f32.
__global__ __launch_bounds__(256) void proj_gemm_kernel(
    const float* __restrict__ x, const ushort* __restrict__ Wcat,
    const float* __restrict__ bcat,
    ushort* __restrict__ q, ushort* __restrict__ kv, ushort* __restrict__ xr,
    float* __restrict__ qwe, int M)
{
  __shared__ __attribute__((aligned(16))) ushort As[64][128];
  __shared__ __attribute__((aligned(16))) ushort Bs[128][128];
  const int tid = threadIdx.x;
  const int rowBase = blockIdx.x * 64;

  // stage A with fused f32->bf16 convert
#pragma unroll
  for (int it = 0; it < 4; ++it) {
    int i = it * 256 + tid;
    int r = i >> 4, c = i & 15;
    int gr = rowBase + r;
    float4 a0 = make_float4(0.f, 0.f, 0.f, 0.f), a1 = a0;
    if (gr < M) {
      a0 = *(const float4*)(x + (size_t)gr * D + c * 8);
      a1 = *(const float4*)(x + (size_t)gr * D + c * 8 + 4);
    }
    uint4 w;
    w.x = (uint)f2b(a0.x) | ((uint)f2b(a0.y) << 16);
    w.y = (uint)f2b(a0.z) | ((uint)f2b(a0.w) << 16);
    w.z = (uint)f2b(a1.x) | ((uint)f2b(a1.y) << 16);
    w.w = (uint)f2b(a1.z) | ((uint)f2b(a1.w) << 16);
    *(uint4*)(&As[r][(c ^ (r & 7)) * 8]) = w;
  }

  const int lane = tid & 63;
  const int wave = tid >> 6;
  const int wm = (wave >> 1) * 32;
  const int wn = (wave & 1) * 64;
  const int lrow = lane & 15;
  const int kgrp = lane >> 4;
  const int orow = (lane >> 4) * 4;
  const int ocol = lane & 15;

  for (int cb = 0; cb < 5; ++cb) {
    // stage B block (cb=4: only rows 0-15 are live)
#pragma unroll
    for (int it = 0; it < 8; ++it) {
      int i = it * 256 + tid;
      int r = i >> 4, c = i & 15;
      if (cb == 4 && r >= 16) continue;
      uint4 bv4 = *(const uint4*)(Wcat + (size_t)(cb * 128 + r) * D + c * 8);
      *(uint4*)(&Bs[r][(c ^ (r & 7)) * 8]) = bv4;
    }
    __syncthreads();

    f32x4 acc[2][4] = {};
#pragma unroll
    for (int ks = 0; ks < 4; ++ks) {
      int chunk = ks * 4 + kgrp;
      bf16x8 a[2], b[4];
#pragma unroll
      for (int m = 0; m < 2; ++m) {
        int r = wm + m * 16 + lrow;
        a[m] = *(const bf16x8*)&As[r][(chunk ^ (r & 7)) * 8];
      }
#pragma unroll
      for (int n = 0; n < 4; ++n) {
        int r = wn + n * 16 + lrow;
        b[n] = *(const bf16x8*)&Bs[r][(chunk ^ (r & 7)) * 8];
      }
#pragma unroll
      for (int m = 0; m < 2; ++m)
#pragma unroll
        for (int n = 0; n < 4; ++n) {
          if (cb == 4 && (wn + n * 16) >= 16) continue;
          acc[m][n] = __builtin_amdgcn_mfma_f32_16x16x32_bf16(a[m], b[n], acc[m][n], 0, 0, 0);
        }
    }

#pragma unroll
    for (int m = 0; m < 2; ++m) {
#pragma unroll
      for (int n = 0; n < 4; ++n) {
        if (cb == 4 && (wn + n * 16) >= 16) continue;
        int col = cb * 128 + wn + n * 16 + ocol;
        float bi = bcat[col];
        int sel = col >> 7, c = col & 127;
#pragma unroll
        for (int ii = 0; ii < 4; ++ii) {
          int gr = rowBase + wm + m * 16 + orow + ii;
          if (gr >= M) continue;
          float v = acc[m][n][ii] + bi;
          if (sel == 0)      q[(size_t)gr * D + c] = f2h(v);
          else if (sel == 1) kv[(size_t)gr * 2 * D + c] = f2h(v);
          else if (sel == 2) kv[(size_t)gr * 2 * D + D + c] = f2h(v);
          else if (sel == 3) xr[(size_t)gr * D + c] = f2b(v);
          else if (c < 16)   qwe[(size_t)gr * 16 + c] = v;
        }
      }
    }
    __syncthreads();
  }
}

// ======================= output projection GEMM (BM=64) =======================
__global__ __launch_bounds__(256) void out_gemm_kernel(
    const ushort* __restrict__ g, const ushort* __restrict__ Wpb,
    const float* __restrict__ bp, float* __restrict__ out, int M)
{
  __shared__ __attribute__((aligned(16))) ushort As[64][128];
  __shared__ __attribute__((aligned(16))) ushort Bs[128][128];
  const int tid = threadIdx.x;
  const int rowBase = blockIdx.x * 64;

#pragma unroll
  for (int it = 0; it < 4; ++it) {
    int i = it * 256 + tid;
    int r = i >> 4, c = i & 15;
    int gr = rowBase + r;
    uint4 av = make_uint4(0, 0, 0, 0);
    if (gr < M) av = *(const uint4*)(g + (size_t)gr * D + c * 8);
    *(uint4*)(&As[r][(c ^ (r & 7)) * 8]) = av;
  }
#pragma unroll
  for (int it = 0; it < 8; ++it) {
    int i = it * 256 + tid;
    int r = i >> 4, c = i & 15;
    uint4 bv4 = *(const uint4*)(Wpb + (size_t)r * D + c * 8);
    *(uint4*)(&Bs[r][(c ^ (r & 7)) * 8]) = bv4;
  }
  __syncthreads();

  const int lane = tid & 63;
  const int wave = tid >> 6;
  const int wm = (wave >> 1) * 32;
  const int wn = (wave & 1) * 64;
  const int lrow = lane & 15;
  const int kgrp = lane >> 4;

  f32x4 acc[2][4] = {};
#pragma unroll
  for (int ks = 0; ks < 4; ++ks) {
    int chunk = ks * 4 + kgrp;
    bf16x8 a[2], b[4];
#pragma unroll
    for (int m = 0; m < 2; ++m) {
      int r = wm + m * 16 + lrow;
      a[m] = *(const bf16x8*)&As[r][(chunk ^ (r & 7)) * 8];
    }
#pragma unroll
    for (int n = 0; n < 4; ++n) {
      int r = wn + n * 16 + lrow;
      b[n] = *(const bf16x8*)&Bs[r][(chunk ^ (r & 7)) * 8];
    }
#pragma unroll
    for (int m = 0; m < 2; ++m)
#pragma unroll
      for (int n = 0; n < 4; ++n)
        acc[m][n] = __builtin_amdgcn_mfma_f32_16x16x32_bf16(a[m], b[n], acc[m][n], 0, 0, 0);
  }

  const int orow = (lane >> 4) * 4;
  const int ocol = lane & 15;
#pragma unroll
  for (int m = 0; m < 2; ++m) {
#pragma unroll
    for (int n = 0; n < 4; ++n) {
      int col = wn + n * 16 + ocol;
      float bi = bp[col];
#pragma unroll
      for (int ii = 0; ii < 4; ++ii) {
        int gr = rowBase + wm + m * 16 + orow + ii;
        if (gr >= M) continue;
        out[(size_t)gr * D + col] = acc[m][n][ii] + bi;
      }
    }
  }
}

// ======================= per-node attention v7 =======================
// One wave per node; 16-lane groups, 4 edges/batch; modulo-3 pipelined loads;
// f16 K/V with v_dot2_f32_f16; exp2-domain defer-max softmax.
__global__ __launch_bounds__(256) void node_attn_kernel(
    const ushort* __restrict__ q, const ushort* __restrict__ kv,
    const ushort* __restrict__ xr, ushort* __restrict__ g,
    const float* __restrict__ qwe, const uint4* __restrict__ easrt,
    const float* __restrict__ We, const float* __restrict__ Wb,
    const int* __restrict__ off, int N)
{
  const int wid = threadIdx.x >> 6;
  const int lane = threadIdx.x & 63;
  const int node = blockIdx.x * 4 + wid;
  if (node >= N) return;
  const int grp = lane >> 4;
  const int i = lane & 15;
  const int di = i * 8;
  const int head = i >> 3;

  h16x2 qh[4];
  {
    uint4 qa = *(const uint4*)(q + (size_t)node * D + di);
    qh[0] = u2h(qa.x); qh[1] = u2h(qa.y); qh[2] = u2h(qa.z); qh[3] = u2h(qa.w);
  }
  float qw[5];
  {
    const float* qp = qwe + (size_t)node * 16 + head * 8;
    float4 t = *(const float4*)qp;
    qw[0] = t.x; qw[1] = t.y; qw[2] = t.z; qw[3] = t.w; qw[4] = qp[4];
  }

  const int beg = off[node], end = off[node + 1];
  float m = -INFINITY, s = 0.f;
  float o[8] = {0.f, 0.f, 0.f, 0.f, 0.f, 0.f, 0.f, 0.f};
  float wea[5] = {0.f, 0.f, 0.f, 0.f, 0.f};

  if (beg < end) {
    const int em1 = end - 1;
    const int p0 = beg + grp;
    uint4 e0 = easrt[min(p0, em1)];
    uint4 e1 = easrt[min(p0 + 4, em1)];
    uint4 e2 = easrt[min(p0 + 8, em1)];
    const ushort* kp_;
    kp_ = kv + (size_t)e0.w * (2 * D);
    uint4 k0 = *(const uint4*)(kp_ + di), v0 = *(const uint4*)(kp_ + D + di);
    kp_ = kv + (size_t)e1.w * (2 * D);
    uint4 k1 = *(const uint4*)(kp_ + di), v1 = *(const uint4*)(kp_ + D + di);
    uint4 k2v = k0, v2v = v0;   // written by STEP1 before STEP3 reads them

#define ATT_STEP(PB, eA, eC, kA, vA, kC, vC)                                   \
    {                                                                          \
      int p = (PB) + grp;                                                      \
      bool valid = p < end;                                                    \
      const ushort* kpn = kv + (size_t)(eC).w * (2 * D);                       \
      (kC) = *(const uint4*)(kpn + di);                                        \
      (vC) = *(const uint4*)(kpn + D + di);                                    \
      float ea0 = blo((eA).x), ea1 = bhi((eA).x), ea2 = blo((eA).y),           \
            ea3 = bhi((eA).y), ea4 = blo((eA).z);                              \
      (eA) = easrt[min(p + 12, em1)];                                          \
      float part = FDOT2(qh[0], u2h((kA).x), 0.f);                             \
      part = FDOT2(qh[1], u2h((kA).y), part);                                  \
      part = FDOT2(qh[2], u2h((kA).z), part);                                  \
      part = FDOT2(qh[3], u2h((kA).w), part);                                  \
      part += __shfl_xor(part, 1, 64);                                         \
      part += __shfl_xor(part, 2, 64);                                         \
      part += __shfl_xor(part, 4, 64);                                         \
      float eadot = qw[0] * ea0 + qw[1] * ea1 + qw[2] * ea2 + qw[3] * ea3      \
                  + qw[4] * ea4;                                               \
      float alpha = valid ? (part + eadot) : -INFINITY;                        \
      h16x2 va = u2h((vA).x), vb = u2h((vA).y), vc = u2h((vA).z),              \
            vd = u2h((vA).w);                                                  \
      float vv0 = (float)va[0], vv1 = (float)va[1], vv2 = (float)vb[0],        \
            vv3 = (float)vb[1], vv4 = (float)vc[0], vv5 = (float)vc[1],        \
            vv6 = (float)vd[0], vv7 = (float)vd[1];                            \
      if (__any(alpha > m + 11.5f)) {                                          \
        float nm = fmaxf(m, alpha);                                            \
        float scale = (m > -1e30f) ? fexp2(m - nm) : 0.f;                      \
        float pw = valid ? fexp2(alpha - nm) : 0.f;                            \
        m = nm;                                                                \
        s = s * scale + pw;                                                    \
        o[0] = o[0] * scale + pw * vv0; o[1] = o[1] * scale + pw * vv1;        \
        o[2] = o[2] * scale + pw * vv2; o[3] = o[3] * scale + pw * vv3;        \
        o[4] = o[4] * scale + pw * vv4; o[5] = o[5] * scale + pw * vv5;        \
        o[6] = o[6] * scale + pw * vv6; o[7] = o[7] * scale + pw * vv7;        \
        wea[0] = wea[0] * scale + pw * ea0; wea[1] = wea[1] * scale + pw * ea1;\
        wea[2] = wea[2] * scale + pw * ea2; wea[3] = wea[3] * scale + pw * ea3;\
        wea[4] = wea[4] * scale + pw * ea4;                                    \
      } else {                                                                 \
        float pw = valid ? fexp2(alpha - m) : 0.f;                             \
        s += pw;                                                               \
        o[0] += pw * vv0; o[1] += pw * vv1; o[2] += pw * vv2;                  \
        o[3] += pw * vv3; o[4] += pw * vv4; o[5] += pw * vv5;                  \
        o[6] += pw * vv6; o[7] += pw * vv7;                                    \
        wea[0] += pw * ea0; wea[1] += pw * ea1; wea[2] += pw * ea2;            \
        wea[3] += pw * ea3; wea[4] += pw * ea4;                                \
      }                                                                        \
    }

    for (int pb = beg; pb < end; pb += 12) {
      ATT_STEP(pb,     e0, e2, k0, v0, k2v, v2v)
      ATT_STEP(pb + 4, e1, e0, k1, v1, k0, v0)
      ATT_STEP(pb + 8, e2, e1, k2v, v2v, k1, v1)
    }
#undef ATT_STEP
  }

  // merge the 4 groups (lane bits 4,5)
#pragma unroll
  for (int ofs = 16; ofs < 64; ofs <<= 1) {
    float m2 = __shfl_xor(m, ofs, 64);
    float s2 = __shfl_xor(s, ofs, 64);
    float o2[8], w2[5];
#pragma unroll
    for (int j = 0; j < 8; ++j) o2[j] = __shfl_xor(o[j], ofs, 64);
#pragma unroll
    for (int j = 0; j < 5; ++j) w2[j] = __shfl_xor(wea[j], ofs, 64);
    float nm = fmaxf(m, m2);
    float e1m = (m > -1e30f) ? fexp2(m - nm) : 0.f;
    float e2m = (m2 > -1e30f) ? fexp2(m2 - nm) : 0.f;
    s = s * e1m + s2 * e2m;
#pragma unroll
    for (int j = 0; j < 8; ++j) o[j] = o[j] * e1m + o2[j] * e2m;
#pragma unroll
    for (int j = 0; j < 5; ++j) wea[j] = wea[j] * e1m + w2[j] * e2m;
    m = nm;
  }

  float inv = (s > 0.f) ? (1.f / s) : 0.f;
#pragma unroll
  for (int j = 0; j < 8; ++j) o[j] *= inv;
#pragma unroll
  for (int j = 0; j < 5; ++j) wea[j] *= inv;

  // O += We @ wea for this lane's 8 dims
  {
    const float* wp = We + (size_t)di * EDIM;
    float4 w[10];
#pragma unroll
    for (int t = 0; t < 10; ++t) w[t] = *(const float4*)(wp + 4 * t);
#pragma unroll
    for (int r = 0; r < 8; ++r)
#pragma unroll
      for (int j = 0; j < 5; ++j) {
        int idx = r * 5 + j;
        o[r] += wea[j] * ((const float*)&w[idx >> 2])[idx & 3];
      }
  }

  // beta gate
  float xrv[8];
  {
    uint4 xa = *(const uint4*)(xr + (size_t)node * D + di);
    xrv[0] = blo(xa.x); xrv[1] = bhi(xa.x); xrv[2] = blo(xa.y); xrv[3] = bhi(xa.y);
    xrv[4] = blo(xa.z); xrv[5] = bhi(xa.z); xrv[6] = blo(xa.w); xrv[7] = bhi(xa.w);
  }
  float part = 0.f;
#pragma unroll
  for (int r = 0; r < 8; ++r) {
    float w1 = Wb[di + r] + Wb[256 + di + r];
    float w2 = Wb[128 + di + r] - Wb[256 + di + r];
    part += o[r] * w1 + xrv[r] * w2;
  }
#pragma unroll
  for (int ofs = 1; ofs < 16; ofs <<= 1) part += __shfl_xor(part, ofs, 64);
  float beta = 1.f / (1.f + __expf(-part));

  if (grp == 0) {
    uint pk[4];
#pragma unroll
    for (int r = 0; r < 4; ++r) {
      float g0 = beta * xrv[2 * r] + (1.f - beta) * o[2 * r];
      float g1 = beta * xrv[2 * r + 1] + (1.f - beta) * o[2 * r + 1];
      pk[r] = (uint)f2b(g0) | ((uint)f2b(g1) << 16);
    }
    *(uint4*)(g + (size_t)node * D + di) = make_uint4(pk[0], pk[1], pk[2], pk[3]);
  }
}

// ======================= launch =======================

extern "C" void kernel_launch(void* const* d_in, const int* in_sizes, int n_in,
                              void* d_out, int out_size, void* d_ws, size_t ws_size,
                              hipStream_t stream)
{
  const float* x  = (const float*)d_in[0];
  const int*   ei = (const int*)d_in[1];
  const float* ea = (const float*)d_in[2];
  const float* Wq = (const float*)d_in[3];
  const float* bq = (const float*)d_in[4];
  const float* Wk = (const float*)d_in[5];
  const float* bk = (const float*)d_in[6];
  const float* Wv = (const float*)d_in[7];
  const float* bv = (const float*)d_in[8];
  const float* We = (const float*)d_in[9];
  const float* Wr = (const float*)d_in[10];
  const float* br = (const float*)d_in[11];
  const float* Wb = (const float*)d_in[12];
  const float* Wp = (const float*)d_in[13];
  const float* bp = (const float*)d_in[14];

  const int N = in_sizes[0] / D;
  const int E = in_sizes[1] / 2;
  float* out = (float*)d_out;

  char* ws = (char*)d_ws;
  size_t o = 0;
  auto alloc = [&](size_t bytes) -> void* {
    void* p = ws + o;
    o = (o + bytes + 255) & ~(size_t)255;
    return p;
  };
  ushort* q      = (ushort*)alloc((size_t)N * D * sizeof(ushort));
  ushort* kv     = (ushort*)alloc((size_t)N * 2 * D * sizeof(ushort));
  ushort* xr     = (ushort*)alloc((size_t)N * D * sizeof(ushort));
  ushort* g      = (ushort*)alloc((size_t)N * D * sizeof(ushort));
  float*  qwe    = (float*)alloc((size_t)N * 16 * sizeof(float));
  ushort* Wcat   = (ushort*)alloc((size_t)640 * D * sizeof(ushort));
  float*  bcat   = (float*)alloc(640 * sizeof(float));
  ushort* Wpb    = (ushort*)alloc((size_t)D * D * sizeof(ushort));
  int*    deg    = (int*)alloc((size_t)N * sizeof(int));
  int*    cursor = (int*)alloc((size_t)N * sizeof(int));
  int*    offs   = (int*)alloc((size_t)(N + 1) * sizeof(int));
  uint4*  easrt  = (uint4*)alloc((size_t)E * sizeof(uint4));
  int*    bsum   = (int*)alloc(64 * sizeof(int));
  int*    bbase  = (int*)alloc(64 * sizeof(int));

  const int n4 = N / 4;                    // N divisible by 4
  const int nb = (n4 + 255) / 256;         // scan blocks (<= 64)

  // weight prep first (also zeroes deg)
  cvt_w_kernel<<<(512 * D + 128 * D + 255) / 256, 256, 0, stream>>>(
      Wq, Wk, Wv, Wr, bq, bk, bv, br, We, Wp, Wcat, bcat, Wpb, deg, N);

  hist_kernel<<<(E + 255) / 256, 256, 0, stream>>>(ei, deg, E);
  scan_p1<<<nb, 256, 0, stream>>>(deg, offs, bsum, n4);
  scan_p2<<<1, 64, 0, stream>>>(bsum, bbase, offs + N, nb);
  scan_p3<<<nb, 256, 0, stream>>>(offs, bbase, cursor, n4);
  scatter_kernel<<<(E + 255) / 256, 256, 0, stream>>>(ei, ea, offs, cursor, easrt, E);

  proj_gemm_kernel<<<(N + 63) / 64, 256, 0, stream>>>(x, Wcat, bcat, q, kv, xr, qwe, N);

  node_attn_kernel<<<(N + 3) / 4, 256, 0, stream>>>(q, kv, xr, g, qwe, easrt, We, Wb,
                                                    offs, N);

  out_gemm_kernel<<<(N + 63) / 64, 256, 0, stream>>>(g, Wpb, bp, out, N);
}